// Round 7
// baseline (189.835 us; speedup 1.0000x reference)
//
#include <hip/hip_runtime.h>
#include <hip/hip_cooperative_groups.h>
#include <math.h>

namespace cg = cooperative_groups;

#define NC 10
#define NP 128
#define ND 512
#define GAMMA  0.1f
#define BCONST 10.0f
#define TAO    1.0f
#define LAMBDA 0.1f
#define THR2   1600.0f     // THRESHOLD^2 (compare d2 instead of sqrt(d2))
#define FEPS   1e-6f
#define NLDS   12          // fallback: proto slots 1..NLDS in LDS; slot 0 in regs; rest global
#define CH     16          // speculation chunk size
#define MAXCH  512         // per-class chunk stride (separate-kernel path only)
#define IMAX   0x7FFFFFFF
#define NBLK   256         // cooperative grid: 1 block/CU -> always co-resident
#define NWAVES (NBLK * 4)

__device__ __forceinline__ float allredf(float v) {
#pragma unroll
  for (int m = 1; m < 64; m <<= 1) v += __shfl_xor(v, m, 64);
  return v;
}

// ===========================================================================
// PATH 1: single cooperative kernel (4 grid syncs, zero kernel boundaries)
// ===========================================================================
struct SOrd { int lab[8192]; int wtot[4][NC]; };
struct SFb  { float ls_proto[NLDS][ND]; int ls_cnt[NP]; };
union  SMem { SOrd ord; SFb fb; };

__global__ __launch_bounds__(256, 2)
void fused_kernel(const float* __restrict__ feats, const int* __restrict__ labels, int B,
                  float* __restrict__ gproto, float* __restrict__ p2s, float* __restrict__ sps,
                  float* __restrict__ chunksum,
                  int* __restrict__ cls_base, int* __restrict__ cls_cnt,
                  int* __restrict__ chunk_base, int* __restrict__ nchtot_g,
                  int* __restrict__ fail_pos, int* __restrict__ nproto_g,
                  int* __restrict__ order, float* __restrict__ out)
{
  cg::grid_group grid = cg::this_grid();
  __shared__ SMem sm;
  __shared__ float bsum[4];

  const int t = threadIdx.x, lane = t & 63, wid = t >> 6;
  const int gwid = blockIdx.x * 4 + wid;

  // ---- Phase 1 (block 0 only): ord + resets (proven round-5 code) ----
  if (blockIdx.x == 0) {
    const int w = wid;
    if (t < NC) { fail_pos[t] = IMAX; nproto_g[t] = 0; }
    if (t == 0) out[0] = 0.f;

    const int4* lp = (const int4*)labels;
    for (int i = t; i < (B >> 2); i += 256) {
      int4 v = lp[i];
      sm.ord.lab[i*4+0] = v.x; sm.ord.lab[i*4+1] = v.y;
      sm.ord.lab[i*4+2] = v.z; sm.ord.lab[i*4+3] = v.w;
    }
    for (int i = (B & ~3) + t; i < B; i += 256) sm.ord.lab[i] = labels[i];
    __syncthreads();

    const int segsz = (B + 255) >> 8;
    const int s0 = t * segsz, s1 = min(s0 + segsz, B);

    int loc[NC];
#pragma unroll
    for (int c = 0; c < NC; ++c) loc[c] = 0;
    for (int i = s0; i < s1; ++i) {
      int l = sm.ord.lab[i];
#pragma unroll
      for (int c = 0; c < NC; ++c) loc[c] += (l == c) ? 1 : 0;
    }

    int pre[NC];
#pragma unroll
    for (int c = 0; c < NC; ++c) pre[c] = loc[c];
#pragma unroll
    for (int m = 1; m < 64; m <<= 1) {
#pragma unroll
      for (int c = 0; c < NC; ++c) {
        int u = __shfl_up(pre[c], m, 64);
        if (lane >= m) pre[c] += u;
      }
    }
    if (lane == 63) {
#pragma unroll
      for (int c = 0; c < NC; ++c) sm.ord.wtot[w][c] = pre[c];
    }
    __syncthreads();

    int pos[NC];
    {
      int cb = 0, crun = 0;
#pragma unroll
      for (int c = 0; c < NC; ++c) {
        int tot = sm.ord.wtot[0][c] + sm.ord.wtot[1][c] + sm.ord.wtot[2][c] + sm.ord.wtot[3][c];
        int before = 0;
#pragma unroll
        for (int ww = 0; ww < 4; ++ww) before += (ww < w) ? sm.ord.wtot[ww][c] : 0;
        pos[c] = cb + before + (pre[c] - loc[c]);
        if (t == 0) { cls_base[c] = cb; cls_cnt[c] = tot; chunk_base[c] = crun; }
        cb += tot;
        crun += (tot + CH - 1) / CH;
      }
      if (t == 0) nchtot_g[0] = crun;
    }

    for (int i = s0; i < s1; ++i) {
      int l = sm.ord.lab[i];
#pragma unroll
      for (int c = 0; c < NC; ++c)
        if (l == c) order[pos[c]++] = i;
    }
  }
  grid.sync();

  int chbv[NC];
#pragma unroll
  for (int c = 0; c < NC; ++c) chbv[c] = chunk_base[c];
  const int nchtot = nchtot_g[0];

  // ---- Phase 2: chunk sums (one wave per 16-sample chunk, compact rows) ----
  for (int fid = gwid; fid < nchtot; fid += NWAVES) {
    int c = 0;
    while (c + 1 < NC && chbv[c + 1] <= fid) ++c;
    const int g = fid - chbv[c];
    const int cnt = cls_cnt[c], base = cls_base[c];
    const int k0 = g * CH, k1 = min(k0 + CH, cnt);
    int myidx = (lane < CH && k0 + lane < cnt) ? order[base + k0 + lane] : 0;

    float S[8] = {0, 0, 0, 0, 0, 0, 0, 0};
    int k = k0;
    for (; k + 4 <= k1; k += 4) {
      float4 A[4], Bv[4];
#pragma unroll
      for (int j = 0; j < 4; ++j) {
        int idx = __shfl(myidx, k + j - k0, 64);
        const float4* fp = (const float4*)(feats + (size_t)idx * ND + lane * 8);
        A[j] = fp[0]; Bv[j] = fp[1];
      }
#pragma unroll
      for (int j = 0; j < 4; ++j) {
        S[0]+=A[j].x; S[1]+=A[j].y; S[2]+=A[j].z; S[3]+=A[j].w;
        S[4]+=Bv[j].x; S[5]+=Bv[j].y; S[6]+=Bv[j].z; S[7]+=Bv[j].w;
      }
    }
    for (; k < k1; ++k) {
      int idx = __shfl(myidx, k - k0, 64);
      const float4* fp = (const float4*)(feats + (size_t)idx * ND + lane * 8);
      float4 a = fp[0], b = fp[1];
      S[0]+=a.x; S[1]+=a.y; S[2]+=a.z; S[3]+=a.w;
      S[4]+=b.x; S[5]+=b.y; S[6]+=b.z; S[7]+=b.w;
    }
    float4* cp = (float4*)(chunksum + (size_t)fid * ND + lane * 8);
    cp[0] = make_float4(S[0], S[1], S[2], S[3]);
    cp[1] = make_float4(S[4], S[5], S[6], S[7]);
  }
  grid.sync();

  // ---- Phase 3: verify + speculative finalize ----
  for (int fid = gwid; fid < nchtot; fid += NWAVES) {
    int c = 0;
    while (c + 1 < NC && chbv[c + 1] <= fid) ++c;
    const int g = fid - chbv[c];
    const int cnt = cls_cnt[c], base = cls_base[c];
    const int nch = (cnt + CH - 1) / CH;
    const int k0 = g * CH, k1 = min(k0 + CH, cnt);
    int myidx = (lane < CH && k0 + lane < cnt) ? order[base + k0 + lane] : 0;

    float P[8] = {0, 0, 0, 0, 0, 0, 0, 0};
    {
      const float* cbase = chunksum + (size_t)chbv[c] * ND + lane * 8;
      int j = 0;
      for (; j + 4 <= g; j += 4) {
        float4 A[4], Bv[4];
#pragma unroll
        for (int q = 0; q < 4; ++q) {
          const float4* pp = (const float4*)(cbase + (size_t)(j + q) * ND);
          A[q] = pp[0]; Bv[q] = pp[1];
        }
#pragma unroll
        for (int q = 0; q < 4; ++q) {
          P[0]+=A[q].x; P[1]+=A[q].y; P[2]+=A[q].z; P[3]+=A[q].w;
          P[4]+=Bv[q].x; P[5]+=Bv[q].y; P[6]+=Bv[q].z; P[7]+=Bv[q].w;
        }
      }
      for (; j < g; ++j) {
        const float4* pp = (const float4*)(cbase + (size_t)j * ND);
        float4 a = pp[0], b = pp[1];
        P[0]+=a.x; P[1]+=a.y; P[2]+=a.z; P[3]+=a.w;
        P[4]+=b.x; P[5]+=b.y; P[6]+=b.z; P[7]+=b.w;
      }
    }

    int k = k0;
    for (; k + 4 <= k1; k += 4) {
      float4 A[4], Bv[4];
#pragma unroll
      for (int j = 0; j < 4; ++j) {
        int idx = __shfl(myidx, k + j - k0, 64);
        const float4* fp = (const float4*)(feats + (size_t)idx * ND + lane * 8);
        A[j] = fp[0]; Bv[j] = fp[1];
      }
      float part[4];
#pragma unroll
      for (int j = 0; j < 4; ++j) {
        int kk = k + j;
        float f[8] = {A[j].x, A[j].y, A[j].z, A[j].w, Bv[j].x, Bv[j].y, Bv[j].z, Bv[j].w};
        if (kk > 0) {
          float inv = 1.f / (float)kk;
          float p = 0.f;
#pragma unroll
          for (int e = 0; e < 8; ++e) { float d = f[e] - P[e] * inv + FEPS; p += d * d; }
          part[j] = p;
        } else part[j] = 0.f;
#pragma unroll
        for (int e = 0; e < 8; ++e) P[e] += f[e];
      }
#pragma unroll
      for (int m = 1; m < 64; m <<= 1) {
#pragma unroll
        for (int j = 0; j < 4; ++j) part[j] += __shfl_xor(part[j], m, 64);
      }
      if (lane == 0) {
#pragma unroll
        for (int j = 0; j < 4; ++j) {
          int kk = k + j;
          if (kk > 0 && !(part[j] < THR2)) atomicMin(&fail_pos[c], kk);
        }
      }
    }
    for (; k < k1; ++k) {
      int idx = __shfl(myidx, k - k0, 64);
      const float4* fp = (const float4*)(feats + (size_t)idx * ND + lane * 8);
      float4 fa = fp[0], fb = fp[1];
      float f[8] = {fa.x, fa.y, fa.z, fa.w, fb.x, fb.y, fb.z, fb.w};
      if (k > 0) {
        float inv = 1.f / (float)k;
        float p = 0.f;
#pragma unroll
        for (int e = 0; e < 8; ++e) { float d = f[e] - P[e] * inv + FEPS; p += d * d; }
        float d2 = allredf(p);
        if (!(d2 < THR2) && lane == 0) atomicMin(&fail_pos[c], k);
      }
#pragma unroll
      for (int e = 0; e < 8; ++e) P[e] += f[e];
    }

    if (g == nch - 1 && cnt > 0) {
      float inv = 1.f / (float)cnt;
      float p[8];
#pragma unroll
      for (int e = 0; e < 8; ++e) p[e] = P[e] * inv;
      float4* gp = (float4*)(gproto + (size_t)c * NP * ND + lane * 8);
      gp[0] = make_float4(p[0], p[1], p[2], p[3]);
      gp[1] = make_float4(p[4], p[5], p[6], p[7]);
      float P2p = 0.f, SPp = 0.f;
#pragma unroll
      for (int e = 0; e < 8; ++e) { P2p += p[e]*p[e]; SPp += p[e]; }
      float P2 = allredf(P2p), SP = allredf(SPp);
      if (lane == 0) { p2s[c*NP] = P2; sps[c*NP] = SP; nproto_g[c] = 1; }
    }
  }
  grid.sync();

  // ---- Phase 4: faithful sequential fallback (block c, wave 0; no-op if ok) ----
  if (wid == 0 && blockIdx.x < NC && fail_pos[blockIdx.x] != IMAX) {
    const int c = blockIdx.x;
    const int base = cls_base[c], cnt = cls_cnt[c];
    float p0[8];
    int cnt0 = 0, n = 0;
    float fA[8], fB[8], fC[8];

    auto LOADF = [&](float (&buf)[8], int m) {
      int idx = order[base + m];
      const float4* fp = (const float4*)(feats + (size_t)idx * ND + lane * 8);
      float4 a = fp[0], b = fp[1];
      buf[0]=a.x; buf[1]=a.y; buf[2]=a.z; buf[3]=a.w;
      buf[4]=b.x; buf[5]=b.y; buf[6]=b.z; buf[7]=b.w;
    };
    auto STEP = [&](float (&f)[8]) {
      float best = 3.4e38f;
      int bidx = 0;
      if (n > 0) {
        float part = 0.f;
#pragma unroll
        for (int e = 0; e < 8; ++e) { float d = f[e] - p0[e] + FEPS; part += d * d; }
        best = allredf(part);
        for (int j = 1; j < n; ++j) {
          float pj[8];
          if (j <= NLDS) {
            const float4* pp = (const float4*)(&sm.fb.ls_proto[j-1][lane*8]);
            float4 a = pp[0], b = pp[1];
            pj[0]=a.x; pj[1]=a.y; pj[2]=a.z; pj[3]=a.w;
            pj[4]=b.x; pj[5]=b.y; pj[6]=b.z; pj[7]=b.w;
          } else {
            const float4* pp = (const float4*)(gproto + ((size_t)c*NP + j)*ND + lane*8);
            float4 a = pp[0], b = pp[1];
            pj[0]=a.x; pj[1]=a.y; pj[2]=a.z; pj[3]=a.w;
            pj[4]=b.x; pj[5]=b.y; pj[6]=b.z; pj[7]=b.w;
          }
          float part2 = 0.f;
#pragma unroll
          for (int e = 0; e < 8; ++e) { float d = f[e] - pj[e] + FEPS; part2 += d * d; }
          float tot = allredf(part2);
          if (tot < best) { best = tot; bidx = j; }
        }
      }
      if (n > 0 && best < THR2) {
        if (bidx == 0) {
          float cc = (float)cnt0, inv = 1.f / (cc + 1.f);
#pragma unroll
          for (int e = 0; e < 8; ++e) p0[e] = (p0[e]*cc + f[e]) * inv;
          cnt0++;
        } else {
          int ci = sm.fb.ls_cnt[bidx];
          float cc = (float)ci, inv = 1.f / (cc + 1.f);
          if (bidx <= NLDS) {
            float* row = &sm.fb.ls_proto[bidx-1][lane*8];
#pragma unroll
            for (int e = 0; e < 8; ++e) row[e] = (row[e]*cc + f[e]) * inv;
          } else {
            float* row = gproto + ((size_t)c*NP + bidx)*ND + lane*8;
#pragma unroll
            for (int e = 0; e < 8; ++e) row[e] = (row[e]*cc + f[e]) * inv;
          }
          if (lane == 0) sm.fb.ls_cnt[bidx] = ci + 1;
        }
      } else {
        int app = min(n, NP - 1);
        if (app == 0) {
#pragma unroll
          for (int e = 0; e < 8; ++e) p0[e] = f[e];
          cnt0 = 1;
        } else if (app <= NLDS) {
          float* row = &sm.fb.ls_proto[app-1][lane*8];
#pragma unroll
          for (int e = 0; e < 8; ++e) row[e] = f[e];
          if (lane == 0) sm.fb.ls_cnt[app] = 1;
        } else {
          float* row = gproto + ((size_t)c*NP + app)*ND + lane*8;
#pragma unroll
          for (int e = 0; e < 8; ++e) row[e] = f[e];
          if (lane == 0) sm.fb.ls_cnt[app] = 1;
        }
        n = min(n + 1, NP);
      }
    };

    if (cnt > 0) LOADF(fA, 0);
    if (cnt > 1) LOADF(fB, 1);
    if (cnt > 2) LOADF(fC, 2);
    int m = 0;
    while (m < cnt) {
      STEP(fA); ++m; if (m + 2 < cnt) LOADF(fA, m + 2);
      if (m >= cnt) break;
      STEP(fB); ++m; if (m + 2 < cnt) LOADF(fB, m + 2);
      if (m >= cnt) break;
      STEP(fC); ++m; if (m + 2 < cnt) LOADF(fC, m + 2);
    }

    for (int j = 0; j < n; ++j) {
      float pj[8];
      if (j == 0) {
#pragma unroll
        for (int e = 0; e < 8; ++e) pj[e] = p0[e];
      } else if (j <= NLDS) {
        const float4* pp = (const float4*)(&sm.fb.ls_proto[j-1][lane*8]);
        float4 a = pp[0], b = pp[1];
        pj[0]=a.x; pj[1]=a.y; pj[2]=a.z; pj[3]=a.w;
        pj[4]=b.x; pj[5]=b.y; pj[6]=b.z; pj[7]=b.w;
      } else {
        const float4* pp = (const float4*)(gproto + ((size_t)c*NP + j)*ND + lane*8);
        float4 a = pp[0], b = pp[1];
        pj[0]=a.x; pj[1]=a.y; pj[2]=a.z; pj[3]=a.w;
        pj[4]=b.x; pj[5]=b.y; pj[6]=b.z; pj[7]=b.w;
      }
      float4* gp = (float4*)(gproto + ((size_t)c*NP + j)*ND + lane*8);
      gp[0] = make_float4(pj[0], pj[1], pj[2], pj[3]);
      gp[1] = make_float4(pj[4], pj[5], pj[6], pj[7]);
      float P2p = 0.f, SPp = 0.f;
#pragma unroll
      for (int e = 0; e < 8; ++e) { P2p += pj[e]*pj[e]; SPp += pj[e]; }
      float P2 = allredf(P2p), SP = allredf(SPp);
      if (lane == 0) { p2s[c*NP + j] = P2; sps[c*NP + j] = SP; }
    }
    if (lane == 0) nproto_g[c] = n;
  }
  grid.sync();

  // ---- Phase 5: loss ----
  {
    int np[NC]; bool fast = true;
#pragma unroll
    for (int cc = 0; cc < NC; ++cc) { np[cc] = nproto_g[cc]; fast &= (np[cc] == 1); }
    float acc = 0.f;

    if (fast) {
      float p2v[NC], spv[NC];
#pragma unroll
      for (int cc = 0; cc < NC; ++cc) { p2v[cc] = p2s[cc*NP]; spv[cc] = sps[cc*NP]; }
      for (int b = gwid; b < B; b += NWAVES) {
        const float4* fp = (const float4*)(feats + (size_t)b * ND + lane * 8);
        float4 a4 = fp[0], b4 = fp[1];
        float f[8] = {a4.x, a4.y, a4.z, a4.w, b4.x, b4.y, b4.z, b4.w};
        int lab = labels[b];

        float v[12];
#pragma unroll
        for (int cc = 0; cc < NC; ++cc) {
          const float4* pp = (const float4*)(gproto + (size_t)cc * NP * ND + lane * 8);
          float4 pa = pp[0], pb = pp[1];
          v[cc] = f[0]*pa.x + f[1]*pa.y + f[2]*pa.z + f[3]*pa.w
                + f[4]*pb.x + f[5]*pb.y + f[6]*pb.z + f[7]*pb.w;
        }
        float f2p = 0.f, sfp = 0.f;
#pragma unroll
        for (int e = 0; e < 8; ++e) { f2p += f[e]*f[e]; sfp += f[e]; }
        v[10] = f2p; v[11] = sfp;
#pragma unroll
        for (int m = 1; m < 64; m <<= 1) {
#pragma unroll
          for (int q = 0; q < 12; ++q) v[q] += __shfl_xor(v[q], m, 64);
        }
        float f2 = v[10], sf = v[11];

        float one = 0.f, num = 0.f, pw = 0.f;
#pragma unroll
        for (int cc = 0; cc < NC; ++cc) {
          float d2 = f2 + p2v[cc] - 2.f*v[cc]
                   + 2.f*FEPS*(sf - spv[cc]) + (float)ND*FEPS*FEPS;
          d2 = fmaxf(d2, 0.f);
          float e = expf(-GAMMA * d2);
          one += e;
          if (cc == lab) num = e;
          float dmin = sqrtf(d2);
          float sign = (cc == lab) ? 1.f : -1.f;
          float z = BCONST - (TAO - dmin) * sign;
          float gg = (z > 10.f) ? z : log1pf(expf(z));
          pw += gg;
        }
        float prob = 1e-6f + ((one > 0.f) ? num / one : one);
        acc += -logf(prob) + LAMBDA * pw;
      }
    } else {
      for (int b = gwid; b < B; b += NWAVES) {
        const float4* fp = (const float4*)(feats + (size_t)b * ND + lane * 8);
        float4 a4 = fp[0], b4 = fp[1];
        float f[8] = {a4.x, a4.y, a4.z, a4.w, b4.x, b4.y, b4.z, b4.w};
        float f2p = 0.f, sfp = 0.f;
#pragma unroll
        for (int e = 0; e < 8; ++e) { f2p += f[e]*f[e]; sfp += f[e]; }
        float f2 = allredf(f2p);
        float sf = allredf(sfp);
        int lab = labels[b];

        float one = 0.f, num = 0.f, pw = 0.f;
        for (int cc = 0; cc < NC; ++cc) {
          int nn = np[cc];
          if (nn <= 0) continue;
          float sume = 0.f, bestd2 = 3.4e38f;
          for (int j = 0; j < nn; ++j) {
            const float4* pp = (const float4*)(gproto + ((size_t)cc*NP + j)*ND + lane*8);
            float4 pa = pp[0], pb = pp[1];
            float dp = f[0]*pa.x + f[1]*pa.y + f[2]*pa.z + f[3]*pa.w
                     + f[4]*pb.x + f[5]*pb.y + f[6]*pb.z + f[7]*pb.w;
            float dot = allredf(dp);
            float d2 = f2 + p2s[cc*NP + j] - 2.f*dot
                     + 2.f*FEPS*(sf - sps[cc*NP + j]) + (float)ND*FEPS*FEPS;
            d2 = fmaxf(d2, 0.f);
            sume  += expf(-GAMMA * d2);
            bestd2 = fminf(bestd2, d2);
          }
          one += sume;
          if (cc == lab) num = sume;
          float dmin = sqrtf(bestd2);
          float sign = (cc == lab) ? 1.f : -1.f;
          float z = BCONST - (TAO - dmin) * sign;
          float g = (z > 10.f) ? z : log1pf(expf(z));
          pw += g;
        }
        float prob = 1e-6f + ((one > 0.f) ? num / one : one);
        acc += -logf(prob) + LAMBDA * pw;
      }
    }

    if (lane == 0) bsum[wid] = acc;
    __syncthreads();
    if (t == 0) atomicAdd(out, bsum[0] + bsum[1] + bsum[2] + bsum[3]);
  }
}

// ===========================================================================
// PATH 2: proven round-5 multi-kernel fallback (used only if coop launch fails)
// ===========================================================================
__global__ __launch_bounds__(256)
void ord_kernel(const int* __restrict__ labels, int B,
                int* __restrict__ order, int* __restrict__ cls_base,
                int* __restrict__ cls_cnt, int* __restrict__ fail_pos,
                int* __restrict__ nproto_g, float* __restrict__ out)
{
  __shared__ int lab[8192];
  __shared__ int wtot[4][NC];
  const int t = threadIdx.x, lane = t & 63, w = t >> 6;

  if (t < NC) { fail_pos[t] = IMAX; nproto_g[t] = 0; }
  if (t == 0) out[0] = 0.f;

  const int4* lp = (const int4*)labels;
  for (int i = t; i < (B >> 2); i += 256) {
    int4 v = lp[i];
    lab[i*4+0] = v.x; lab[i*4+1] = v.y; lab[i*4+2] = v.z; lab[i*4+3] = v.w;
  }
  for (int i = (B & ~3) + t; i < B; i += 256) lab[i] = labels[i];
  __syncthreads();

  const int segsz = (B + 255) >> 8;
  const int s0 = t * segsz, s1 = min(s0 + segsz, B);

  int loc[NC];
#pragma unroll
  for (int c = 0; c < NC; ++c) loc[c] = 0;
  for (int i = s0; i < s1; ++i) {
    int l = lab[i];
#pragma unroll
    for (int c = 0; c < NC; ++c) loc[c] += (l == c) ? 1 : 0;
  }

  int pre[NC];
#pragma unroll
  for (int c = 0; c < NC; ++c) pre[c] = loc[c];
#pragma unroll
  for (int m = 1; m < 64; m <<= 1) {
#pragma unroll
    for (int c = 0; c < NC; ++c) {
      int u = __shfl_up(pre[c], m, 64);
      if (lane >= m) pre[c] += u;
    }
  }
  if (lane == 63) {
#pragma unroll
    for (int c = 0; c < NC; ++c) wtot[w][c] = pre[c];
  }
  __syncthreads();

  int pos[NC];
  {
    int cb = 0;
#pragma unroll
    for (int c = 0; c < NC; ++c) {
      int tot = wtot[0][c] + wtot[1][c] + wtot[2][c] + wtot[3][c];
      int before = 0;
#pragma unroll
      for (int ww = 0; ww < 4; ++ww) before += (ww < w) ? wtot[ww][c] : 0;
      pos[c] = cb + before + (pre[c] - loc[c]);
      if (t == 0) { cls_base[c] = cb; cls_cnt[c] = tot; }
      cb += tot;
    }
  }
  for (int i = s0; i < s1; ++i) {
    int l = lab[i];
#pragma unroll
    for (int c = 0; c < NC; ++c)
      if (l == c) order[pos[c]++] = i;
  }
}

__global__ __launch_bounds__(64)
void chunksum_kernel(const float* __restrict__ feats, const int* __restrict__ order,
                     const int* __restrict__ cls_base, const int* __restrict__ cls_cnt,
                     float* __restrict__ chunksum)
{
  const int c = blockIdx.x / MAXCH, g = blockIdx.x % MAXCH;
  const int cnt = cls_cnt[c];
  const int nch = (cnt + CH - 1) / CH;
  if (g >= nch) return;
  const int base = cls_base[c], lane = threadIdx.x;
  const int k0 = g * CH, k1 = min(k0 + CH, cnt);
  int myidx = (lane < CH && k0 + lane < cnt) ? order[base + k0 + lane] : 0;

  float S[8] = {0, 0, 0, 0, 0, 0, 0, 0};
  int k = k0;
  for (; k + 4 <= k1; k += 4) {
    float4 A[4], Bv[4];
#pragma unroll
    for (int j = 0; j < 4; ++j) {
      int idx = __shfl(myidx, k + j - k0, 64);
      const float4* fp = (const float4*)(feats + (size_t)idx * ND + lane * 8);
      A[j] = fp[0]; Bv[j] = fp[1];
    }
#pragma unroll
    for (int j = 0; j < 4; ++j) {
      S[0]+=A[j].x; S[1]+=A[j].y; S[2]+=A[j].z; S[3]+=A[j].w;
      S[4]+=Bv[j].x; S[5]+=Bv[j].y; S[6]+=Bv[j].z; S[7]+=Bv[j].w;
    }
  }
  for (; k < k1; ++k) {
    int idx = __shfl(myidx, k - k0, 64);
    const float4* fp = (const float4*)(feats + (size_t)idx * ND + lane * 8);
    float4 a = fp[0], b = fp[1];
    S[0]+=a.x; S[1]+=a.y; S[2]+=a.z; S[3]+=a.w;
    S[4]+=b.x; S[5]+=b.y; S[6]+=b.z; S[7]+=b.w;
  }
  float4* cp = (float4*)(chunksum + ((size_t)c * MAXCH + g) * ND + lane * 8);
  cp[0] = make_float4(S[0], S[1], S[2], S[3]);
  cp[1] = make_float4(S[4], S[5], S[6], S[7]);
}

__global__ __launch_bounds__(64)
void verify_kernel(const float* __restrict__ feats, const int* __restrict__ order,
                   const int* __restrict__ cls_base, const int* __restrict__ cls_cnt,
                   const float* __restrict__ chunksum, int* __restrict__ fail_pos,
                   float* __restrict__ gproto, float* __restrict__ p2s,
                   float* __restrict__ sps, int* __restrict__ nproto_g)
{
  const int c = blockIdx.x / MAXCH, g = blockIdx.x % MAXCH;
  const int cnt = cls_cnt[c];
  const int nch = (cnt + CH - 1) / CH;
  if (g >= nch) return;
  const int base = cls_base[c], lane = threadIdx.x;
  const int k0 = g * CH, k1 = min(k0 + CH, cnt);
  int myidx = (lane < CH && k0 + lane < cnt) ? order[base + k0 + lane] : 0;

  float P[8] = {0, 0, 0, 0, 0, 0, 0, 0};
  {
    const float* cbase = chunksum + (size_t)c * MAXCH * ND + lane * 8;
    int j = 0;
    for (; j + 4 <= g; j += 4) {
      float4 A[4], Bv[4];
#pragma unroll
      for (int q = 0; q < 4; ++q) {
        const float4* pp = (const float4*)(cbase + (size_t)(j + q) * ND);
        A[q] = pp[0]; Bv[q] = pp[1];
      }
#pragma unroll
      for (int q = 0; q < 4; ++q) {
        P[0]+=A[q].x; P[1]+=A[q].y; P[2]+=A[q].z; P[3]+=A[q].w;
        P[4]+=Bv[q].x; P[5]+=Bv[q].y; P[6]+=Bv[q].z; P[7]+=Bv[q].w;
      }
    }
    for (; j < g; ++j) {
      const float4* pp = (const float4*)(cbase + (size_t)j * ND);
      float4 a = pp[0], b = pp[1];
      P[0]+=a.x; P[1]+=a.y; P[2]+=a.z; P[3]+=a.w;
      P[4]+=b.x; P[5]+=b.y; P[6]+=b.z; P[7]+=b.w;
    }
  }

  int k = k0;
  for (; k + 4 <= k1; k += 4) {
    float4 A[4], Bv[4];
#pragma unroll
    for (int j = 0; j < 4; ++j) {
      int idx = __shfl(myidx, k + j - k0, 64);
      const float4* fp = (const float4*)(feats + (size_t)idx * ND + lane * 8);
      A[j] = fp[0]; Bv[j] = fp[1];
    }
    float part[4];
#pragma unroll
    for (int j = 0; j < 4; ++j) {
      int kk = k + j;
      float f[8] = {A[j].x, A[j].y, A[j].z, A[j].w, Bv[j].x, Bv[j].y, Bv[j].z, Bv[j].w};
      if (kk > 0) {
        float inv = 1.f / (float)kk;
        float p = 0.f;
#pragma unroll
        for (int e = 0; e < 8; ++e) { float d = f[e] - P[e] * inv + FEPS; p += d * d; }
        part[j] = p;
      } else part[j] = 0.f;
#pragma unroll
      for (int e = 0; e < 8; ++e) P[e] += f[e];
    }
#pragma unroll
    for (int m = 1; m < 64; m <<= 1) {
#pragma unroll
      for (int j = 0; j < 4; ++j) part[j] += __shfl_xor(part[j], m, 64);
    }
    if (lane == 0) {
#pragma unroll
      for (int j = 0; j < 4; ++j) {
        int kk = k + j;
        if (kk > 0 && !(part[j] < THR2)) atomicMin(&fail_pos[c], kk);
      }
    }
  }
  for (; k < k1; ++k) {
    int idx = __shfl(myidx, k - k0, 64);
    const float4* fp = (const float4*)(feats + (size_t)idx * ND + lane * 8);
    float4 fa = fp[0], fb = fp[1];
    float f[8] = {fa.x, fa.y, fa.z, fa.w, fb.x, fb.y, fb.z, fb.w};
    if (k > 0) {
      float inv = 1.f / (float)k;
      float p = 0.f;
#pragma unroll
      for (int e = 0; e < 8; ++e) { float d = f[e] - P[e] * inv + FEPS; p += d * d; }
      float d2 = allredf(p);
      if (!(d2 < THR2) && lane == 0) atomicMin(&fail_pos[c], k);
    }
#pragma unroll
    for (int e = 0; e < 8; ++e) P[e] += f[e];
  }

  if (g == nch - 1) {
    float inv = 1.f / (float)cnt;
    float p[8];
#pragma unroll
    for (int e = 0; e < 8; ++e) p[e] = P[e] * inv;
    float4* gp = (float4*)(gproto + (size_t)c * NP * ND + lane * 8);
    gp[0] = make_float4(p[0], p[1], p[2], p[3]);
    gp[1] = make_float4(p[4], p[5], p[6], p[7]);
    float P2p = 0.f, SPp = 0.f;
#pragma unroll
    for (int e = 0; e < 8; ++e) { P2p += p[e]*p[e]; SPp += p[e]; }
    float P2 = allredf(P2p), SP = allredf(SPp);
    if (lane == 0) { p2s[c*NP] = P2; sps[c*NP] = SP; nproto_g[c] = 1; }
  }
}

__global__ __launch_bounds__(64)
void fallback_kernel(const float* __restrict__ feats, const int* __restrict__ order,
                     const int* __restrict__ cls_base, const int* __restrict__ cls_cnt,
                     const int* __restrict__ fail_pos,
                     float* __restrict__ gproto, float* __restrict__ p2s,
                     float* __restrict__ sps, int* __restrict__ nproto_g)
{
  const int c = blockIdx.x;
  if (fail_pos[c] == IMAX) return;

  __shared__ float ls_proto[NLDS][ND];
  __shared__ int   ls_cnt[NP];
  const int lane = threadIdx.x;
  const int base = cls_base[c], cnt = cls_cnt[c];

  float p0[8];
  int cnt0 = 0, n = 0;
  float fA[8], fB[8], fC[8];

  auto LOADF = [&](float (&buf)[8], int m) {
    int idx = order[base + m];
    const float4* fp = (const float4*)(feats + (size_t)idx * ND + lane * 8);
    float4 a = fp[0], b = fp[1];
    buf[0]=a.x; buf[1]=a.y; buf[2]=a.z; buf[3]=a.w;
    buf[4]=b.x; buf[5]=b.y; buf[6]=b.z; buf[7]=b.w;
  };
  auto STEP = [&](float (&f)[8]) {
    float best = 3.4e38f;
    int bidx = 0;
    if (n > 0) {
      float part = 0.f;
#pragma unroll
      for (int e = 0; e < 8; ++e) { float d = f[e] - p0[e] + FEPS; part += d * d; }
      best = allredf(part);
      for (int j = 1; j < n; ++j) {
        float pj[8];
        if (j <= NLDS) {
          const float4* pp = (const float4*)(&ls_proto[j-1][lane*8]);
          float4 a = pp[0], b = pp[1];
          pj[0]=a.x; pj[1]=a.y; pj[2]=a.z; pj[3]=a.w;
          pj[4]=b.x; pj[5]=b.y; pj[6]=b.z; pj[7]=b.w;
        } else {
          const float4* pp = (const float4*)(gproto + ((size_t)c*NP + j)*ND + lane*8);
          float4 a = pp[0], b = pp[1];
          pj[0]=a.x; pj[1]=a.y; pj[2]=a.z; pj[3]=a.w;
          pj[4]=b.x; pj[5]=b.y; pj[6]=b.z; pj[7]=b.w;
        }
        float part2 = 0.f;
#pragma unroll
        for (int e = 0; e < 8; ++e) { float d = f[e] - pj[e] + FEPS; part2 += d * d; }
        float tot = allredf(part2);
        if (tot < best) { best = tot; bidx = j; }
      }
    }
    if (n > 0 && best < THR2) {
      if (bidx == 0) {
        float cc = (float)cnt0, inv = 1.f / (cc + 1.f);
#pragma unroll
        for (int e = 0; e < 8; ++e) p0[e] = (p0[e]*cc + f[e]) * inv;
        cnt0++;
      } else {
        int ci = ls_cnt[bidx];
        float cc = (float)ci, inv = 1.f / (cc + 1.f);
        if (bidx <= NLDS) {
          float* row = &ls_proto[bidx-1][lane*8];
#pragma unroll
          for (int e = 0; e < 8; ++e) row[e] = (row[e]*cc + f[e]) * inv;
        } else {
          float* row = gproto + ((size_t)c*NP + bidx)*ND + lane*8;
#pragma unroll
          for (int e = 0; e < 8; ++e) row[e] = (row[e]*cc + f[e]) * inv;
        }
        if (lane == 0) ls_cnt[bidx] = ci + 1;
      }
    } else {
      int app = min(n, NP - 1);
      if (app == 0) {
#pragma unroll
        for (int e = 0; e < 8; ++e) p0[e] = f[e];
        cnt0 = 1;
      } else if (app <= NLDS) {
        float* row = &ls_proto[app-1][lane*8];
#pragma unroll
        for (int e = 0; e < 8; ++e) row[e] = f[e];
        if (lane == 0) ls_cnt[app] = 1;
      } else {
        float* row = gproto + ((size_t)c*NP + app)*ND + lane*8;
#pragma unroll
        for (int e = 0; e < 8; ++e) row[e] = f[e];
        if (lane == 0) ls_cnt[app] = 1;
      }
      n = min(n + 1, NP);
    }
  };

  if (cnt > 0) LOADF(fA, 0);
  if (cnt > 1) LOADF(fB, 1);
  if (cnt > 2) LOADF(fC, 2);
  int m = 0;
  while (m < cnt) {
    STEP(fA); ++m; if (m + 2 < cnt) LOADF(fA, m + 2);
    if (m >= cnt) break;
    STEP(fB); ++m; if (m + 2 < cnt) LOADF(fB, m + 2);
    if (m >= cnt) break;
    STEP(fC); ++m; if (m + 2 < cnt) LOADF(fC, m + 2);
  }

  for (int j = 0; j < n; ++j) {
    float pj[8];
    if (j == 0) {
#pragma unroll
      for (int e = 0; e < 8; ++e) pj[e] = p0[e];
    } else if (j <= NLDS) {
      const float4* pp = (const float4*)(&ls_proto[j-1][lane*8]);
      float4 a = pp[0], b = pp[1];
      pj[0]=a.x; pj[1]=a.y; pj[2]=a.z; pj[3]=a.w;
      pj[4]=b.x; pj[5]=b.y; pj[6]=b.z; pj[7]=b.w;
    } else {
      const float4* pp = (const float4*)(gproto + ((size_t)c*NP + j)*ND + lane*8);
      float4 a = pp[0], b = pp[1];
      pj[0]=a.x; pj[1]=a.y; pj[2]=a.z; pj[3]=a.w;
      pj[4]=b.x; pj[5]=b.y; pj[6]=b.z; pj[7]=b.w;
    }
    float4* gp = (float4*)(gproto + ((size_t)c*NP + j)*ND + lane*8);
    gp[0] = make_float4(pj[0], pj[1], pj[2], pj[3]);
    gp[1] = make_float4(pj[4], pj[5], pj[6], pj[7]);
    float P2p = 0.f, SPp = 0.f;
#pragma unroll
    for (int e = 0; e < 8; ++e) { P2p += pj[e]*pj[e]; SPp += pj[e]; }
    float P2 = allredf(P2p), SP = allredf(SPp);
    if (lane == 0) { p2s[c*NP + j] = P2; sps[c*NP + j] = SP; }
  }
  if (lane == 0) nproto_g[c] = n;
}

__global__ __launch_bounds__(256)
void loss_kernel(const float* __restrict__ feats, const int* __restrict__ labels, int B,
                 const float* __restrict__ gproto, const float* __restrict__ p2s,
                 const float* __restrict__ sps, const int* __restrict__ nproto_g,
                 float* __restrict__ out)
{
  __shared__ float bsum[4];
  const int lane = threadIdx.x & 63;
  const int wid  = threadIdx.x >> 6;
  const int gw   = blockIdx.x * 4 + wid;
  const int nw   = gridDim.x * 4;

  int np[NC];
  bool fast = true;
#pragma unroll
  for (int cc = 0; cc < NC; ++cc) { np[cc] = nproto_g[cc]; fast &= (np[cc] == 1); }

  float acc = 0.f;
  if (fast) {
    float p2v[NC], spv[NC];
#pragma unroll
    for (int cc = 0; cc < NC; ++cc) { p2v[cc] = p2s[cc*NP]; spv[cc] = sps[cc*NP]; }
    for (int b = gw; b < B; b += nw) {
      const float4* fp = (const float4*)(feats + (size_t)b * ND + lane * 8);
      float4 a4 = fp[0], b4 = fp[1];
      float f[8] = {a4.x, a4.y, a4.z, a4.w, b4.x, b4.y, b4.z, b4.w};
      int lab = labels[b];
      float v[12];
#pragma unroll
      for (int cc = 0; cc < NC; ++cc) {
        const float4* pp = (const float4*)(gproto + (size_t)cc * NP * ND + lane * 8);
        float4 pa = pp[0], pb = pp[1];
        v[cc] = f[0]*pa.x + f[1]*pa.y + f[2]*pa.z + f[3]*pa.w
              + f[4]*pb.x + f[5]*pb.y + f[6]*pb.z + f[7]*pb.w;
      }
      float f2p = 0.f, sfp = 0.f;
#pragma unroll
      for (int e = 0; e < 8; ++e) { f2p += f[e]*f[e]; sfp += f[e]; }
      v[10] = f2p; v[11] = sfp;
#pragma unroll
      for (int m = 1; m < 64; m <<= 1) {
#pragma unroll
        for (int q = 0; q < 12; ++q) v[q] += __shfl_xor(v[q], m, 64);
      }
      float f2 = v[10], sf = v[11];
      float one = 0.f, num = 0.f, pw = 0.f;
#pragma unroll
      for (int cc = 0; cc < NC; ++cc) {
        float d2 = f2 + p2v[cc] - 2.f*v[cc]
                 + 2.f*FEPS*(sf - spv[cc]) + (float)ND*FEPS*FEPS;
        d2 = fmaxf(d2, 0.f);
        float e = expf(-GAMMA * d2);
        one += e;
        if (cc == lab) num = e;
        float dmin = sqrtf(d2);
        float sign = (cc == lab) ? 1.f : -1.f;
        float z = BCONST - (TAO - dmin) * sign;
        float gg = (z > 10.f) ? z : log1pf(expf(z));
        pw += gg;
      }
      float prob = 1e-6f + ((one > 0.f) ? num / one : one);
      acc += -logf(prob) + LAMBDA * pw;
    }
  } else {
    for (int b = gw; b < B; b += nw) {
      const float4* fp = (const float4*)(feats + (size_t)b * ND + lane * 8);
      float4 a4 = fp[0], b4 = fp[1];
      float f[8] = {a4.x, a4.y, a4.z, a4.w, b4.x, b4.y, b4.z, b4.w};
      float f2p = 0.f, sfp = 0.f;
#pragma unroll
      for (int e = 0; e < 8; ++e) { f2p += f[e]*f[e]; sfp += f[e]; }
      float f2 = allredf(f2p);
      float sf = allredf(sfp);
      int lab = labels[b];
      float one = 0.f, num = 0.f, pw = 0.f;
      for (int cc = 0; cc < NC; ++cc) {
        int nn = np[cc];
        if (nn <= 0) continue;
        float sume = 0.f, bestd2 = 3.4e38f;
        for (int j = 0; j < nn; ++j) {
          const float4* pp = (const float4*)(gproto + ((size_t)cc*NP + j)*ND + lane*8);
          float4 pa = pp[0], pb = pp[1];
          float dp = f[0]*pa.x + f[1]*pa.y + f[2]*pa.z + f[3]*pa.w
                   + f[4]*pb.x + f[5]*pb.y + f[6]*pb.z + f[7]*pb.w;
          float dot = allredf(dp);
          float d2 = f2 + p2s[cc*NP + j] - 2.f*dot
                   + 2.f*FEPS*(sf - sps[cc*NP + j]) + (float)ND*FEPS*FEPS;
          d2 = fmaxf(d2, 0.f);
          sume  += expf(-GAMMA * d2);
          bestd2 = fminf(bestd2, d2);
        }
        one += sume;
        if (cc == lab) num = sume;
        float dmin = sqrtf(bestd2);
        float sign = (cc == lab) ? 1.f : -1.f;
        float z = BCONST - (TAO - dmin) * sign;
        float g = (z > 10.f) ? z : log1pf(expf(z));
        pw += g;
      }
      float prob = 1e-6f + ((one > 0.f) ? num / one : one);
      acc += -logf(prob) + LAMBDA * pw;
    }
  }

  if (lane == 0) bsum[wid] = acc;
  __syncthreads();
  if (threadIdx.x == 0) atomicAdd(out, bsum[0] + bsum[1] + bsum[2] + bsum[3]);
}

// ---------------------------------------------------------------------------
extern "C" void kernel_launch(void* const* d_in, const int* in_sizes, int n_in,
                              void* d_out, int out_size, void* d_ws, size_t ws_size,
                              hipStream_t stream) {
  const float* feats  = (const float*)d_in[0];
  const int*   labels = (const int*)d_in[1];
  int B = in_sizes[0] / ND;   // 8192

  float* gproto   = (float*)d_ws;                        // NC*NP*ND
  float* p2s      = gproto + (size_t)NC * NP * ND;       // NC*NP
  float* sps      = p2s + NC * NP;                       // NC*NP
  float* chunksum = sps + NC * NP;                       // NC*MAXCH*ND (superset of compact rows)
  int*   nproto_g = (int*)(chunksum + (size_t)NC * MAXCH * ND); // NC
  int*   order    = nproto_g + NC;                       // B
  int*   cls_base = order + B;                           // NC
  int*   cls_cnt  = cls_base + NC;                       // NC
  int*   fail_pos = cls_cnt + NC;                        // NC
  int*   chunk_base = fail_pos + NC;                     // NC
  int*   nchtot_g = chunk_base + NC;                     // 1
  float* outf     = (float*)d_out;

  void* args[] = { (void*)&feats, (void*)&labels, (void*)&B,
                   (void*)&gproto, (void*)&p2s, (void*)&sps, (void*)&chunksum,
                   (void*)&cls_base, (void*)&cls_cnt, (void*)&chunk_base,
                   (void*)&nchtot_g, (void*)&fail_pos, (void*)&nproto_g,
                   (void*)&order, (void*)&outf };
  hipError_t err = hipLaunchCooperativeKernel((const void*)fused_kernel,
                                              dim3(NBLK), dim3(256), args, 0, stream);
  if (err != hipSuccess) {
    (void)hipGetLastError();   // clear sticky error, fall back to multi-kernel path
    hipLaunchKernelGGL(ord_kernel, dim3(1), dim3(256), 0, stream,
                       labels, B, order, cls_base, cls_cnt, fail_pos,
                       nproto_g, outf);
    hipLaunchKernelGGL(chunksum_kernel, dim3(NC * MAXCH), dim3(64), 0, stream,
                       feats, order, cls_base, cls_cnt, chunksum);
    hipLaunchKernelGGL(verify_kernel, dim3(NC * MAXCH), dim3(64), 0, stream,
                       feats, order, cls_base, cls_cnt, chunksum, fail_pos,
                       gproto, p2s, sps, nproto_g);
    hipLaunchKernelGGL(fallback_kernel, dim3(NC), dim3(64), 0, stream,
                       feats, order, cls_base, cls_cnt, fail_pos,
                       gproto, p2s, sps, nproto_g);
    hipLaunchKernelGGL(loss_kernel, dim3(2048), dim3(256), 0, stream,
                       feats, labels, B, gproto, p2s, sps, nproto_g, outf);
  }
}